// Round 7
// baseline (236.428 us; speedup 1.0000x reference)
//
#include <hip/hip_runtime.h>

// OTAM cumulative distance on MI355X (gfx950) — wave-role-split version.
// Per (q,s) pair: 16x16 tile, D = 1 - sim. Two banded soft-min DPs
// (forward and transposed); out = -0.5*(F+T).
//
// Block = 128 threads = 2 waves covering 64 pairs:
//   wave 0: forward DP for pairs [base..base+63]   (row recurrence, up[18])
//   wave 1: transposed DP for the same pairs       (column sweep, S[16])
// Branch is wave-uniform (no divergence). Results combined via 64-float LDS.
// Both waves stream the tile row-by-row (transposed DP column jj=l+1 consumes
// original row l), so HBM traffic is one pass; wave 1 rides wave 0's L1 lines.
//
// Math in scaled u-domain: u = -cum/(lbda*ln2). softmin -> logsumexp2:
//   u' = max(u1,u2) + log2(1 + 2^(min-max)) + rk,   rk = (sim-1)*KSC <= 0
// F = -CL2 * uF, so out = -0.5*(F+T) = 0.5*CL2*(uF + uT).

#define KSC  14.426950408889634f    // 1/(lbda*ln2), lbda = 0.1
#define HCL2 0.034657359027997264f  // 0.5 * lbda * ln2

#if __has_builtin(__builtin_amdgcn_exp2f)
static __device__ __forceinline__ float fexp2(float x) { return __builtin_amdgcn_exp2f(x); }
#else
static __device__ __forceinline__ float fexp2(float x) {
    float r; asm("v_exp_f32 %0, %1" : "=v"(r) : "v"(x)); return r;
}
#endif
#if __has_builtin(__builtin_amdgcn_logf)
static __device__ __forceinline__ float flog2(float x) { return __builtin_amdgcn_logf(x); }
#else
static __device__ __forceinline__ float flog2(float x) {
    float r; asm("v_log_f32 %0, %1" : "=v"(r) : "v"(x)); return r;
}
#endif

static __device__ __forceinline__ float lse2(float x, float y) {
    float mx = fmaxf(x, y), mn = fminf(x, y);
    return mx + flog2(1.0f + fexp2(mn - mx));
}
static __device__ __forceinline__ float lse3(float x, float y, float z) {
    float mx = fmaxf(fmaxf(x, y), z);   // -> v_max3_f32
    float s  = fexp2(x - mx) + fexp2(y - mx) + fexp2(z - mx);
    return mx + flog2(s);
}

#define UNPACKK(rk, b0, b1, b2, b3)                                              \
    rk[0]=(b0.x-1.0f)*KSC;  rk[1]=(b0.y-1.0f)*KSC;  rk[2]=(b0.z-1.0f)*KSC;       \
    rk[3]=(b0.w-1.0f)*KSC;  rk[4]=(b1.x-1.0f)*KSC;  rk[5]=(b1.y-1.0f)*KSC;       \
    rk[6]=(b1.z-1.0f)*KSC;  rk[7]=(b1.w-1.0f)*KSC;  rk[8]=(b2.x-1.0f)*KSC;       \
    rk[9]=(b2.y-1.0f)*KSC;  rk[10]=(b2.z-1.0f)*KSC; rk[11]=(b2.w-1.0f)*KSC;      \
    rk[12]=(b3.x-1.0f)*KSC; rk[13]=(b3.y-1.0f)*KSC; rk[14]=(b3.z-1.0f)*KSC;      \
    rk[15]=(b3.w-1.0f)*KSC

#define PIPE_ADVANCE(l)                                                          \
    b0 = c0; b1 = c1; b2 = c2; b3 = c3;                                          \
    c0 = e0; c1 = e1; c2 = e2; c3 = e3;                                          \
    if ((l) + 2 < 16) {                                                          \
        e0 = tp[((l) + 2) * 4 + 0]; e1 = tp[((l) + 2) * 4 + 1];                  \
        e2 = tp[((l) + 2) * 4 + 2]; e3 = tp[((l) + 2) * 4 + 3];                  \
    }

__global__ __launch_bounds__(128) void otam_kernel(const float* __restrict__ sim,
                                                   float* __restrict__ out,
                                                   int npairs) {
    __shared__ float tshare[64];
    const int lane = threadIdx.x & 63;
    const int wid  = threadIdx.x >> 6;          // 0 = forward, 1 = transposed
    int p = blockIdx.x * 64 + lane;
    if (p >= npairs) p = npairs - 1;            // clamp; 160000 % 64 == 0 so never taken
    const float4* tp = (const float4*)(sim + (size_t)p * 256);

    float rk[16];
    // 3-row load pipeline: b = current row, c = +1, e = +2 in flight
    float4 b0 = tp[0], b1 = tp[1], b2 = tp[2],  b3 = tp[3];
    float4 c0 = tp[4], c1 = tp[5], c2 = tp[6],  c3 = tp[7];
    float4 e0 = tp[8], e1 = tp[9], e2 = tp[10], e3 = tp[11];

    UNPACKK(rk, b0, b1, b2, b3);

    float resu;  // wave 0: uF
    if (wid == 0) {
        // ---------------- forward DP ----------------
        float up[18];
        up[0] = 0.0f;
#pragma unroll
        for (int m = 1; m <= 16; ++m) up[m] = up[m - 1] + rk[m - 1];
        up[17] = up[16];

        for (int l = 1; l < 16; ++l) {
            PIPE_ADVANCE(l);
            UNPACKK(rk, b0, b1, b2, b3);
            // m = 1 (boundary): softmin(cum[l-1][0]=0, cum[l][0]=0, cum[l-1][1])
            float t   = up[1];
            float cur = lse3(0.0f, 0.0f, t) + rk[0];
            up[1] = cur;
            float a_old = t;
#pragma unroll
            for (int m = 2; m <= 16; ++m) {
                t      = up[m];
                cur    = lse2(a_old, cur) + rk[m - 1];
                up[m]  = cur;
                a_old  = t;
            }
            // m = 17 (boundary, padded d = 0)
            up[17] = lse3(a_old, cur, up[17]);
        }
        resu = up[17];
    } else {
        // ---------------- transposed DP (column sweep) ----------------
        float S[16];
        {   // column jj = 1 (boundary; previous column all zeros)
            float cur = rk[0];
            S[0] = cur;
#pragma unroll
            for (int i = 1; i < 16; ++i) {
                cur  = lse3(0.0f, 0.0f, cur) + rk[i];
                S[i] = cur;
            }
        }
        for (int l = 1; l < 16; ++l) {    // columns jj = 2..16 (never boundary)
            PIPE_ADVANCE(l);
            UNPACKK(rk, b0, b1, b2, b3);
            float po  = S[0];
            float cur = S[0] + rk[0];     // DP-row 0: prefix
            S[0] = cur;
#pragma unroll
            for (int i = 1; i < 16; ++i) {
                float t = S[i];
                cur  = lse2(po, t) + rk[i];
                S[i] = cur;
                po   = t;
            }
        }
        {   // column jj = 17 (boundary, padded d = 0)
            float po = S[0], cur = S[0];
#pragma unroll
            for (int i = 1; i < 16; ++i) {
                float t = S[i];
                cur = lse3(po, t, cur);
                po  = t;
            }
            tshare[lane] = cur;           // uT
        }
        resu = 0.0f;
    }

    __syncthreads();
    if (wid == 0) {
        out[p] = HCL2 * (resu + tshare[lane]);  // -0.5*(F+T)
    }
}

extern "C" void kernel_launch(void* const* d_in, const int* in_sizes, int n_in,
                              void* d_out, int out_size, void* d_ws, size_t ws_size,
                              hipStream_t stream) {
    const float* sim = (const float*)d_in[0];
    float* out       = (float*)d_out;
    int npairs = in_sizes[0] / 256;             // 400*400 = 160000
    int blocks = (npairs + 63) / 64;            // 2500 blocks x 2 waves
    otam_kernel<<<blocks, 128, 0, stream>>>(sim, out, npairs);
}